// Round 4
// baseline (9387.366 us; speedup 1.0000x reference)
//
#include <hip/hip_runtime.h>

// ---------------------------------------------------------------------------
// ComNet: R=16 runs x T=512 steps x 32 agents, sequential agent scan.
//   k0: transpose W1[:, :93] -> w1T
//   k1: pre1[rti][h] = b1[h] + xs(93) . W1xs  (parallel, bulk of FLOPs)
//   k2: wave-synchronous sequential kernel, 16 real blocks x 1 wave
//       + 480 BALLAST blocks (clock-boost experiment, round 4).
// Round-1 lesson: __syncthreads forces vmcnt(0) drains -> removed.
// Round-2 lesson: per-step global store / on-chain readlane -> LDS ring+snapshot.
// Round-3 lesson: ns/step invariant (~480-570) across 3 structurally different
//   kernels while the instruction-level chain model says ~170-210 ns. Suspect
//   low SCLK (DPM) because the chip is ~idle (16 CU, 0.7% VALU). Round 4 keeps
//   the seq body IDENTICAL and adds ballast waves on the other 240 CUs
//   (~2.7 ms of independent FMAs @2.4GHz) to pull the clock up. If total drops
//   to ~4-5 ms the hypothesis is confirmed; if flat, it is dead.
// ---------------------------------------------------------------------------

#define R_RUNS 16
#define T_STEPS 512
#define NA 32
#define HID 64
#define XS 93                       // (NA-1)*3
#define DIN 124
#define STEPS_PER_RUN (T_STEPS * NA)        // 16384
#define RTI_TOT (R_RUNS * STEPS_PER_RUN)    // 262144

#define PRE1_OFF 65536
#define WS_NEEDED ((size_t)PRE1_OFF + (size_t)RTI_TOT * HID * 4 + 4096)

#define BALLAST_BLOCKS 480
#define BALLAST_ITERS 400000        // ~6.4e6 cyc ~= 2.7 ms @ 2.4 GHz

__device__ __forceinline__ float fast_tanh(float x) {
  float xc = fminf(fmaxf(x, -15.f), 15.f);
  float e = __expf(2.f * xc);
  return (e - 1.f) * __builtin_amdgcn_rcpf(e + 1.f);
}

#define DPP_ADD(x, ctrl, rmask) \
  (x) += __int_as_float(__builtin_amdgcn_update_dpp(0, __float_as_int(x), (ctrl), (rmask), 0xf, true))

__device__ __forceinline__ float wave64_sum_bcast(float x) {
  DPP_ADD(x, 0x111, 0xf);
  DPP_ADD(x, 0x112, 0xf);
  DPP_ADD(x, 0x114, 0xf);
  DPP_ADD(x, 0x118, 0xf);
  DPP_ADD(x, 0x142, 0xa);
  DPP_ADD(x, 0x143, 0xc);
  return __int_as_float(__builtin_amdgcn_readlane(__float_as_int(x), 63));
}

// 3 simultaneous wave64 sums. x2's chain interleaved first (only it is on the
// serial critical path), broadcast via readlane; x0/x1 totals land in lane 63.
__device__ __forceinline__ void wave64_sum3_l63(float& x0, float& x1, float& x2) {
#define ST3(ctrl, rmask) \
  DPP_ADD(x2, ctrl, rmask); DPP_ADD(x0, ctrl, rmask); DPP_ADD(x1, ctrl, rmask)
  ST3(0x111, 0xf);  // row_shr:1
  ST3(0x112, 0xf);  // row_shr:2
  ST3(0x114, 0xf);  // row_shr:4
  ST3(0x118, 0xf);  // row_shr:8
  ST3(0x142, 0xa);  // row_bcast:15 -> rows 1,3
  ST3(0x143, 0xc);  // row_bcast:31 -> rows 2,3
#undef ST3
  x2 = __int_as_float(__builtin_amdgcn_readlane(__float_as_int(x2), 63));
}

// ---------------- k0: transpose W1 xs-part ----------------
__global__ void transpose_w1(const float* __restrict__ w1, float* __restrict__ w1T) {
  int idx = blockIdx.x * blockDim.x + threadIdx.x;  // idx = k*64 + h
  if (idx < XS * HID) {
    int k = idx / HID, h = idx % HID;
    w1T[idx] = w1[h * DIN + k];
  }
}

// ---------------- k1: pre1 = b1 + xs @ W1xs^T ----------------
__global__ __launch_bounds__(256) void pre1_kernel(
    const float* __restrict__ runs, const float* __restrict__ w1T,
    const float* __restrict__ b1, float* __restrict__ pre1) {
  const int wid = (blockIdx.x * 256 + threadIdx.x) >> 6;  // rti, one wave each
  const int lane = threadIdx.x & 63;
  const float* xs = runs + (size_t)wid * XS;   // wave-uniform: broadcast loads
  float a0 = b1[lane], a1 = 0.f, a2 = 0.f;
#pragma unroll 4
  for (int k = 0; k < 31; ++k) {
    a0 = fmaf(xs[3 * k],     w1T[(3 * k) * HID + lane],     a0);
    a1 = fmaf(xs[3 * k + 1], w1T[(3 * k + 1) * HID + lane], a1);
    a2 = fmaf(xs[3 * k + 2], w1T[(3 * k + 2) * HID + lane], a2);
  }
  pre1[(size_t)wid * HID + lane] = (a0 + a1) + a2;
}

// ---------------- k2: sequential core (wave-synchronous) + ballast ----------
// A[h][j] = w1[h][93+j] (j<=30, A[h][31]=0) : weight of comm[j] when j<i
// B[h][j] = w1[h][92+j] (j>=1,  B[h][0]=0)  : weight of comm[j] when j>i
// h1pre = pre1 + FB + Q - S; FB = sum_j B*comm_t0[j] (refresh each t),
// S += B[h][i]*old_i (old_i from t-start snapshot), Q += A[h][i]*c_new.
__global__ __launch_bounds__(64, 1) void seq_kernel(
    const float* __restrict__ w1, const float* __restrict__ w2,
    const float* __restrict__ b2, const float* __restrict__ w3,
    const float* __restrict__ b3, const float* __restrict__ comm_init,
    const float* __restrict__ pre1, float* __restrict__ out,
    float* __restrict__ bws) {
  const int h = threadIdx.x;

  if (blockIdx.x >= R_RUNS) {
    // ----- ballast: fixed, deterministic FMA spin to hold SCLK up -----
    float a0 = 1.0f + h * 1e-6f, a1 = a0 + 0.1f, a2 = a0 + 0.2f, a3 = a0 + 0.3f;
    float a4 = a0 + 0.4f, a5 = a0 + 0.5f, a6 = a0 + 0.6f, a7 = a0 + 0.7f;
    for (int it = 0; it < BALLAST_ITERS; ++it) {
      a0 = fmaf(a0, 0.9999999f, 1e-7f);
      a1 = fmaf(a1, 0.9999999f, 1e-7f);
      a2 = fmaf(a2, 0.9999999f, 1e-7f);
      a3 = fmaf(a3, 0.9999999f, 1e-7f);
      a4 = fmaf(a4, 0.9999999f, 1e-7f);
      a5 = fmaf(a5, 0.9999999f, 1e-7f);
      a6 = fmaf(a6, 0.9999999f, 1e-7f);
      a7 = fmaf(a7, 0.9999999f, 1e-7f);
    }
    if (h == 0)
      bws[blockIdx.x] = ((a0 + a1) + (a2 + a3)) + ((a4 + a5) + (a6 + a7));
    return;
  }

  const int r = blockIdx.x;
  const int hb = h * 33;              // stride 33: conflict-free

  __shared__ float Asl[HID * 33];
  __shared__ float Bsl[HID * 33];
  __shared__ __align__(16) float commL[NA];
  __shared__ __align__(16) float h1s[HID];
  __shared__ __align__(16) float2 oL[NA];   // per-t (o0,o1) ring, flushed per t

  for (int j = 0; j < 31; ++j) Asl[hb + j] = w1[h * DIN + 93 + j];
  Asl[hb + 31] = 0.f;
  Bsl[hb] = 0.f;
  for (int j = 1; j < 32; ++j) Bsl[hb + j] = w1[h * DIN + 92 + j];

  float w2r[HID];
#pragma unroll
  for (int k = 0; k < HID; ++k) w2r[k] = w2[h * HID + k];
  const float b2h = b2[h];
  const float w30h = w3[h], w31h = w3[HID + h], w32h = w3[2 * HID + h];
  const float b30 = b3[0], b31 = b3[1], b32 = b3[2];

  float commR = (h < NA) ? comm_init[r * NA + h] : 0.f;  // lane j holds comm[j]
  if (h < NA) commL[h] = commR;                          // mirror for FB refresh

  const float* p = pre1 + (size_t)r * STEPS_PER_RUN * HID + h;
  float pf[4];                         // prefetch ring, depth 4
  pf[0] = p[0]; pf[1] = p[HID]; pf[2] = p[2 * HID]; pf[3] = p[3 * HID];
  float* outw = out + (size_t)r * STEPS_PER_RUN * 2;

  for (int t = 0; t < T_STEPS; ++t) {
    // FB refresh (amortized over 32 steps)
    const float4* cv4 = (const float4*)commL;
    float f0 = 0.f, f1 = 0.f, f2 = 0.f, f3 = 0.f;
#pragma unroll
    for (int q = 0; q < 8; ++q) {
      float4 c = cv4[q];
      f0 = fmaf(Bsl[hb + 4 * q + 0], c.x, f0);
      f1 = fmaf(Bsl[hb + 4 * q + 1], c.y, f1);
      f2 = fmaf(Bsl[hb + 4 * q + 2], c.z, f2);
      f3 = fmaf(Bsl[hb + 4 * q + 3], c.w, f3);
    }
    const float FB = (f0 + f1) + (f2 + f3);
    const float c0s = commR;           // t-start snapshot: old_i source, off-chain
    float Q = 0.f, S = 0.f;

#pragma unroll 4
    for (int i = 0; i < NA; ++i) {
      float pin = p[(i + 4) * HID];    // fire-and-forget prefetch, depth 4
      float A_i = Asl[hb + i];         // off-chain LDS loads
      float B_i = Bsl[hb + i];
      float old_i = __int_as_float(__builtin_amdgcn_readlane(__float_as_int(c0s), i));
      S = fmaf(B_i, old_i, S);         // off the c_new chain (snapshot-based)
      float h1 = fast_tanh(pf[i & 3] + (FB - S) + Q);   // chain: Q enters here
      pf[i & 3] = pin;
      h1s[h] = h1;
      // 64-term dot, 8 accumulator chains
      float a0 = b2h, a1 = 0.f, a2 = 0.f, a3 = 0.f;
      float a4 = 0.f, a5 = 0.f, a6 = 0.f, a7 = 0.f;
      const float4* hv4 = (const float4*)h1s;   // broadcast reads
#pragma unroll
      for (int k4 = 0; k4 < 16; k4 += 2) {
        float4 x = hv4[k4];
        float4 y = hv4[k4 + 1];
        a0 = fmaf(w2r[4 * k4 + 0], x.x, a0);
        a1 = fmaf(w2r[4 * k4 + 1], x.y, a1);
        a2 = fmaf(w2r[4 * k4 + 2], x.z, a2);
        a3 = fmaf(w2r[4 * k4 + 3], x.w, a3);
        a4 = fmaf(w2r[4 * k4 + 4], y.x, a4);
        a5 = fmaf(w2r[4 * k4 + 5], y.y, a5);
        a6 = fmaf(w2r[4 * k4 + 6], y.z, a6);
        a7 = fmaf(w2r[4 * k4 + 7], y.w, a7);
      }
      float h2 = fast_tanh(((a0 + a1) + (a2 + a3)) + ((a4 + a5) + (a6 + a7)));
      float s0 = w30h * h2, s1 = w31h * h2, s2 = w32h * h2;
      wave64_sum3_l63(s0, s1, s2);     // s2 broadcast; s0/s1 total in lane 63
      float c_new = s2 + b32;
      if (h == 63) oL[i] = make_float2(s0 + b30, s1 + b31);  // LDS, off-chain
      Q = fmaf(A_i, c_new, Q);
      commR = (h == i) ? c_new : commR;
      if (h == i) commL[h] = c_new;    // mirror for next t's FB, off-chain
    }
    p += NA * HID;
    // flush this t's 32 x (o0,o1) = 64 floats, one coalesced 256B store.
    outw[h] = ((const float*)oL)[h];
    outw += 2 * NA;
  }
}

// ---------------- fallback: fully fused, zero workspace (unused when ws ok) --
__global__ __launch_bounds__(64, 1) void seq_fused(
    const float* __restrict__ runs, const float* __restrict__ comm_init,
    const float* __restrict__ w1, const float* __restrict__ b1,
    const float* __restrict__ w2, const float* __restrict__ b2,
    const float* __restrict__ w3, const float* __restrict__ b3,
    float* __restrict__ out) {
  const int r = blockIdx.x;
  const int h = threadIdx.x;
  const int hb = h * 33;

  __shared__ float Asl[HID * 33];
  __shared__ float Bsl[HID * 33];
  __shared__ float commL[NA];
  __shared__ __align__(16) float h1s[HID];
  __shared__ float w1xs[XS * HID];
  __shared__ __align__(16) float xsl[96];

  for (int j = 0; j < 31; ++j) Asl[hb + j] = w1[h * DIN + 93 + j];
  Asl[hb + 31] = 0.f;
  Bsl[hb] = 0.f;
  for (int j = 1; j < 32; ++j) Bsl[hb + j] = w1[h * DIN + 92 + j];
  for (int k = 0; k < XS; ++k) w1xs[k * HID + h] = w1[h * DIN + k];

  float w2r[HID];
#pragma unroll
  for (int k = 0; k < HID; ++k) w2r[k] = w2[h * HID + k];
  const float b1h = b1[h];
  const float b2h = b2[h];
  const float w30h = w3[h], w31h = w3[HID + h], w32h = w3[2 * HID + h];
  const float b30 = b3[0], b31 = b3[1], b32 = b3[2];
  if (h < NA) commL[h] = comm_init[r * NA + h];

  const float* xbase = runs + (size_t)r * STEPS_PER_RUN * XS;
  float xa = xbase[h];
  float xb = (h < XS - 64) ? xbase[64 + h] : 0.f;
  float* outp = out + (size_t)r * STEPS_PER_RUN * 2;
  __syncthreads();

  int s = 0;
  for (int t = 0; t < T_STEPS; ++t) {
    float FB = 0.f;
#pragma unroll
    for (int j = 0; j < NA; ++j) FB = fmaf(Bsl[hb + j], commL[j], FB);
    float Q = 0.f, S = 0.f;
    for (int i = 0; i < NA; ++i, ++s) {
      int sn = s + 1; if (sn > STEPS_PER_RUN - 1) sn = STEPS_PER_RUN - 1;
      const float* xn = xbase + (size_t)sn * XS;
      xsl[h] = xa;
      if (h < XS - 64) xsl[64 + h] = xb;
      __syncthreads();
      float xa_n = xn[h];
      float xb_n = (h < XS - 64) ? xn[64 + h] : 0.f;
      float a0 = b1h, a1 = 0.f, a2 = 0.f;
#pragma unroll 4
      for (int k = 0; k < 31; ++k) {
        a0 = fmaf(xsl[3 * k],     w1xs[(3 * k) * HID + h],     a0);
        a1 = fmaf(xsl[3 * k + 1], w1xs[(3 * k + 1) * HID + h], a1);
        a2 = fmaf(xsl[3 * k + 2], w1xs[(3 * k + 2) * HID + h], a2);
      }
      float old_i = commL[i];
      S = fmaf(Bsl[hb + i], old_i, S);
      float h1 = fast_tanh(((a0 + a1) + a2) + FB + Q - S);
      h1s[h] = h1;
      __syncthreads();
      float c0 = b2h, c1 = 0.f, c2 = 0.f, c3 = 0.f;
      const float4* hv4 = (const float4*)h1s;
#pragma unroll
      for (int k4 = 0; k4 < 16; ++k4) {
        float4 hv = hv4[k4];
        c0 = fmaf(w2r[4 * k4 + 0], hv.x, c0);
        c1 = fmaf(w2r[4 * k4 + 1], hv.y, c1);
        c2 = fmaf(w2r[4 * k4 + 2], hv.z, c2);
        c3 = fmaf(w2r[4 * k4 + 3], hv.w, c3);
      }
      float h2 = fast_tanh((c0 + c1) + (c2 + c3));
      float o0 = wave64_sum_bcast(w30h * h2) + b30;
      float o1 = wave64_sum_bcast(w31h * h2) + b31;
      float c_new = wave64_sum_bcast(w32h * h2) + b32;
      if (h == 0) *(float2*)(outp + (size_t)s * 2) = make_float2(o0, o1);
      Q = fmaf(Asl[hb + i], c_new, Q);
      if (h == i) commL[h] = c_new;
      __syncthreads();
      xa = xa_n; xb = xb_n;
    }
  }
}

extern "C" void kernel_launch(void* const* d_in, const int* in_sizes, int n_in,
                              void* d_out, int out_size, void* d_ws, size_t ws_size,
                              hipStream_t stream) {
  const float* runs = (const float*)d_in[0];
  const float* comm_init = (const float*)d_in[1];
  const float* w1 = (const float*)d_in[2];
  const float* b1 = (const float*)d_in[3];
  const float* w2 = (const float*)d_in[4];
  const float* b2 = (const float*)d_in[5];
  const float* w3 = (const float*)d_in[6];
  const float* b3 = (const float*)d_in[7];
  float* out = (float*)d_out;

  if (ws_size >= WS_NEEDED) {
    float* w1T = (float*)d_ws;
    float* pre1 = (float*)((char*)d_ws + PRE1_OFF);
    // ballast scratch: floats at index 8192.. of the w1T 64KB slot
    // (w1T itself uses only 23,808 B; no overlap with pre1)
    float* bws = (float*)d_ws + 8192;
    hipLaunchKernelGGL(transpose_w1, dim3((XS * HID + 255) / 256), dim3(256), 0, stream,
                       w1, w1T);
    hipLaunchKernelGGL(pre1_kernel, dim3(RTI_TOT / 4), dim3(256), 0, stream,
                       runs, w1T, b1, pre1);
    hipLaunchKernelGGL(seq_kernel, dim3(R_RUNS + BALLAST_BLOCKS), dim3(64), 0, stream,
                       w1, w2, b2, w3, b3, comm_init, pre1, out, bws);
  } else {
    hipLaunchKernelGGL(seq_fused, dim3(R_RUNS), dim3(64), 0, stream,
                       runs, comm_init, w1, b1, w2, b2, w3, b3, out);
  }
}

// Round 5
// 7349.107 us; speedup vs baseline: 1.2773x; 1.2773x over previous
//
#include <hip/hip_runtime.h>

// ---------------------------------------------------------------------------
// ComNet: R=16 runs x T=512 steps x 32 agents, sequential agent scan.
//   k0: transpose W1[:, :93] -> w1T
//   k1: pre1[rti][h] = b1[h] + xs(93) . W1xs  (parallel, bulk of FLOPs)
//   k2: wave-synchronous sequential kernel, 16 blocks x 1 wave.
// Round-1: __syncthreads forces vmcnt(0) drains -> removed.
// Round-2: per-step global store / on-chain readlane -> LDS ring + snapshot.
// Round-3: ns/step ~invariant across structural changes -> chain model wrong.
// Round-4: ballast experiment: VALUBusy 0.77->15%, dur FLAT -> clock/DPM
//   hypothesis dead. Evidence VGPR_Count=76 < 64(w2 row)+~30(live scalars):
//   float w2r[64] was never register-promoted (SROA threshold) -> per-step
//   scratch reloads of the W2 row with vmcnt waits ON the serial chain.
// Round-5: force W2 row into VGPRs as 16 NAMED float4s (no array). Ballast
//   removed. Verify via VGPR_Count >= ~120.
// ---------------------------------------------------------------------------

#define R_RUNS 16
#define T_STEPS 512
#define NA 32
#define HID 64
#define XS 93                       // (NA-1)*3
#define DIN 124
#define STEPS_PER_RUN (T_STEPS * NA)        // 16384
#define RTI_TOT (R_RUNS * STEPS_PER_RUN)    // 262144

#define PRE1_OFF 65536
#define WS_NEEDED ((size_t)PRE1_OFF + (size_t)RTI_TOT * HID * 4 + 4096)

__device__ __forceinline__ float fast_tanh(float x) {
  float xc = fminf(fmaxf(x, -15.f), 15.f);
  float e = __expf(2.f * xc);
  return (e - 1.f) * __builtin_amdgcn_rcpf(e + 1.f);
}

#define DPP_ADD(x, ctrl, rmask) \
  (x) += __int_as_float(__builtin_amdgcn_update_dpp(0, __float_as_int(x), (ctrl), (rmask), 0xf, true))

__device__ __forceinline__ float wave64_sum_bcast(float x) {
  DPP_ADD(x, 0x111, 0xf);
  DPP_ADD(x, 0x112, 0xf);
  DPP_ADD(x, 0x114, 0xf);
  DPP_ADD(x, 0x118, 0xf);
  DPP_ADD(x, 0x142, 0xa);
  DPP_ADD(x, 0x143, 0xc);
  return __int_as_float(__builtin_amdgcn_readlane(__float_as_int(x), 63));
}

// 3 simultaneous wave64 sums. x2's chain interleaved first (only it is on the
// serial critical path), broadcast via readlane; x0/x1 totals land in lane 63.
__device__ __forceinline__ void wave64_sum3_l63(float& x0, float& x1, float& x2) {
#define ST3(ctrl, rmask) \
  DPP_ADD(x2, ctrl, rmask); DPP_ADD(x0, ctrl, rmask); DPP_ADD(x1, ctrl, rmask)
  ST3(0x111, 0xf);  // row_shr:1
  ST3(0x112, 0xf);  // row_shr:2
  ST3(0x114, 0xf);  // row_shr:4
  ST3(0x118, 0xf);  // row_shr:8
  ST3(0x142, 0xa);  // row_bcast:15 -> rows 1,3
  ST3(0x143, 0xc);  // row_bcast:31 -> rows 2,3
#undef ST3
  x2 = __int_as_float(__builtin_amdgcn_readlane(__float_as_int(x2), 63));
}

// ---------------- k0: transpose W1 xs-part ----------------
__global__ void transpose_w1(const float* __restrict__ w1, float* __restrict__ w1T) {
  int idx = blockIdx.x * blockDim.x + threadIdx.x;  // idx = k*64 + h
  if (idx < XS * HID) {
    int k = idx / HID, h = idx % HID;
    w1T[idx] = w1[h * DIN + k];
  }
}

// ---------------- k1: pre1 = b1 + xs @ W1xs^T ----------------
__global__ __launch_bounds__(256) void pre1_kernel(
    const float* __restrict__ runs, const float* __restrict__ w1T,
    const float* __restrict__ b1, float* __restrict__ pre1) {
  const int wid = (blockIdx.x * 256 + threadIdx.x) >> 6;  // rti, one wave each
  const int lane = threadIdx.x & 63;
  const float* xs = runs + (size_t)wid * XS;   // wave-uniform: broadcast loads
  float a0 = b1[lane], a1 = 0.f, a2 = 0.f;
#pragma unroll 4
  for (int k = 0; k < 31; ++k) {
    a0 = fmaf(xs[3 * k],     w1T[(3 * k) * HID + lane],     a0);
    a1 = fmaf(xs[3 * k + 1], w1T[(3 * k + 1) * HID + lane], a1);
    a2 = fmaf(xs[3 * k + 2], w1T[(3 * k + 2) * HID + lane], a2);
  }
  pre1[(size_t)wid * HID + lane] = (a0 + a1) + a2;
}

// ---------------- k2: sequential core (wave-synchronous) ----------------
// A[h][j] = w1[h][93+j] (j<=30, A[h][31]=0) : weight of comm[j] when j<i
// B[h][j] = w1[h][92+j] (j>=1,  B[h][0]=0)  : weight of comm[j] when j>i
// h1pre = pre1 + FB + Q - S; FB = sum_j B*comm_t0[j] (refresh each t),
// S += B[h][i]*old_i (old_i from t-start snapshot), Q += A[h][i]*c_new.
__global__ __launch_bounds__(64, 1) void seq_kernel(
    const float* __restrict__ w1, const float* __restrict__ w2,
    const float* __restrict__ b2, const float* __restrict__ w3,
    const float* __restrict__ b3, const float* __restrict__ comm_init,
    const float* __restrict__ pre1, float* __restrict__ out) {
  const int h = threadIdx.x;
  const int r = blockIdx.x;
  const int hb = h * 33;              // stride 33: conflict-free

  __shared__ float Asl[HID * 33];
  __shared__ float Bsl[HID * 33];
  __shared__ __align__(16) float commL[NA];
  __shared__ __align__(16) float h1s[HID];
  __shared__ __align__(16) float2 oL[NA];   // per-t (o0,o1) ring, flushed per t

  for (int j = 0; j < 31; ++j) Asl[hb + j] = w1[h * DIN + 93 + j];
  Asl[hb + 31] = 0.f;
  Bsl[hb] = 0.f;
  for (int j = 1; j < 32; ++j) Bsl[hb + j] = w1[h * DIN + 92 + j];

  // W2 row h in 16 NAMED float4 VGPR quads (no array -> no SROA demotion).
  const float4* w2v = (const float4*)(w2 + h * HID);
  const float4 r0 = w2v[0],  r1 = w2v[1],  r2 = w2v[2],  r3 = w2v[3];
  const float4 r4 = w2v[4],  r5 = w2v[5],  r6 = w2v[6],  r7 = w2v[7];
  const float4 r8 = w2v[8],  r9 = w2v[9],  r10 = w2v[10], r11 = w2v[11];
  const float4 r12 = w2v[12], r13 = w2v[13], r14 = w2v[14], r15 = w2v[15];

  const float b2h = b2[h];
  const float w30h = w3[h], w31h = w3[HID + h], w32h = w3[2 * HID + h];
  const float b30 = b3[0], b31 = b3[1], b32 = b3[2];

  float commR = (h < NA) ? comm_init[r * NA + h] : 0.f;  // lane j holds comm[j]
  if (h < NA) commL[h] = commR;                          // mirror for FB refresh

  const float* p = pre1 + (size_t)r * STEPS_PER_RUN * HID + h;
  float pf[4];                         // prefetch ring, depth 4 (const-indexed)
  pf[0] = p[0]; pf[1] = p[HID]; pf[2] = p[2 * HID]; pf[3] = p[3 * HID];
  float* outw = out + (size_t)r * STEPS_PER_RUN * 2;

  for (int t = 0; t < T_STEPS; ++t) {
    // FB refresh (amortized over 32 steps)
    const float4* cv4 = (const float4*)commL;
    float f0 = 0.f, f1 = 0.f, f2 = 0.f, f3 = 0.f;
#pragma unroll
    for (int q = 0; q < 8; ++q) {
      float4 c = cv4[q];
      f0 = fmaf(Bsl[hb + 4 * q + 0], c.x, f0);
      f1 = fmaf(Bsl[hb + 4 * q + 1], c.y, f1);
      f2 = fmaf(Bsl[hb + 4 * q + 2], c.z, f2);
      f3 = fmaf(Bsl[hb + 4 * q + 3], c.w, f3);
    }
    const float FB = (f0 + f1) + (f2 + f3);
    const float c0s = commR;           // t-start snapshot: old_i source, off-chain
    float Q = 0.f, S = 0.f;

#pragma unroll 4
    for (int i = 0; i < NA; ++i) {
      float pin = p[(i + 4) * HID];    // fire-and-forget prefetch, depth 4
      float A_i = Asl[hb + i];         // off-chain LDS loads
      float B_i = Bsl[hb + i];
      float old_i = __int_as_float(__builtin_amdgcn_readlane(__float_as_int(c0s), i));
      S = fmaf(B_i, old_i, S);         // off the c_new chain (snapshot-based)
      float h1 = fast_tanh(pf[i & 3] + (FB - S) + Q);   // chain: Q enters here
      pf[i & 3] = pin;
      h1s[h] = h1;
      // 64-term dot against the named W2 quads, 8 accumulator chains
      const float4* hv4 = (const float4*)h1s;   // broadcast reads
      float4 x0 = hv4[0], x1 = hv4[1], x2 = hv4[2], x3 = hv4[3];
      float4 x4 = hv4[4], x5 = hv4[5], x6 = hv4[6], x7 = hv4[7];
      float4 x8 = hv4[8], x9 = hv4[9], x10 = hv4[10], x11 = hv4[11];
      float4 x12 = hv4[12], x13 = hv4[13], x14 = hv4[14], x15 = hv4[15];
      float a0 = b2h, a1 = 0.f, a2 = 0.f, a3 = 0.f;
      float a4 = 0.f, a5 = 0.f, a6 = 0.f, a7 = 0.f;
#define DOT4(rq, xq, b0, b1_, b2_, b3_) \
      b0 = fmaf(rq.x, xq.x, b0); b1_ = fmaf(rq.y, xq.y, b1_); \
      b2_ = fmaf(rq.z, xq.z, b2_); b3_ = fmaf(rq.w, xq.w, b3_)
      DOT4(r0, x0, a0, a1, a2, a3);   DOT4(r1, x1, a4, a5, a6, a7);
      DOT4(r2, x2, a0, a1, a2, a3);   DOT4(r3, x3, a4, a5, a6, a7);
      DOT4(r4, x4, a0, a1, a2, a3);   DOT4(r5, x5, a4, a5, a6, a7);
      DOT4(r6, x6, a0, a1, a2, a3);   DOT4(r7, x7, a4, a5, a6, a7);
      DOT4(r8, x8, a0, a1, a2, a3);   DOT4(r9, x9, a4, a5, a6, a7);
      DOT4(r10, x10, a0, a1, a2, a3); DOT4(r11, x11, a4, a5, a6, a7);
      DOT4(r12, x12, a0, a1, a2, a3); DOT4(r13, x13, a4, a5, a6, a7);
      DOT4(r14, x14, a0, a1, a2, a3); DOT4(r15, x15, a4, a5, a6, a7);
#undef DOT4
      float h2 = fast_tanh(((a0 + a1) + (a2 + a3)) + ((a4 + a5) + (a6 + a7)));
      float s0 = w30h * h2, s1 = w31h * h2, s2 = w32h * h2;
      wave64_sum3_l63(s0, s1, s2);     // s2 broadcast; s0/s1 total in lane 63
      float c_new = s2 + b32;
      if (h == 63) oL[i] = make_float2(s0 + b30, s1 + b31);  // LDS, off-chain
      Q = fmaf(A_i, c_new, Q);
      commR = (h == i) ? c_new : commR;
      if (h == i) commL[h] = c_new;    // mirror for next t's FB, off-chain
    }
    p += NA * HID;
    // flush this t's 32 x (o0,o1) = 64 floats, one coalesced 256B store.
    outw[h] = ((const float*)oL)[h];
    outw += 2 * NA;
  }
}

// ---------------- fallback: fully fused, zero workspace (unused when ws ok) --
__global__ __launch_bounds__(64, 1) void seq_fused(
    const float* __restrict__ runs, const float* __restrict__ comm_init,
    const float* __restrict__ w1, const float* __restrict__ b1,
    const float* __restrict__ w2, const float* __restrict__ b2,
    const float* __restrict__ w3, const float* __restrict__ b3,
    float* __restrict__ out) {
  const int r = blockIdx.x;
  const int h = threadIdx.x;
  const int hb = h * 33;

  __shared__ float Asl[HID * 33];
  __shared__ float Bsl[HID * 33];
  __shared__ float commL[NA];
  __shared__ __align__(16) float h1s[HID];
  __shared__ float w1xs[XS * HID];
  __shared__ __align__(16) float xsl[96];

  for (int j = 0; j < 31; ++j) Asl[hb + j] = w1[h * DIN + 93 + j];
  Asl[hb + 31] = 0.f;
  Bsl[hb] = 0.f;
  for (int j = 1; j < 32; ++j) Bsl[hb + j] = w1[h * DIN + 92 + j];
  for (int k = 0; k < XS; ++k) w1xs[k * HID + h] = w1[h * DIN + k];

  float w2r[HID];
#pragma unroll
  for (int k = 0; k < HID; ++k) w2r[k] = w2[h * HID + k];
  const float b1h = b1[h];
  const float b2h = b2[h];
  const float w30h = w3[h], w31h = w3[HID + h], w32h = w3[2 * HID + h];
  const float b30 = b3[0], b31 = b3[1], b32 = b3[2];
  if (h < NA) commL[h] = comm_init[r * NA + h];

  const float* xbase = runs + (size_t)r * STEPS_PER_RUN * XS;
  float xa = xbase[h];
  float xb = (h < XS - 64) ? xbase[64 + h] : 0.f;
  float* outp = out + (size_t)r * STEPS_PER_RUN * 2;
  __syncthreads();

  int s = 0;
  for (int t = 0; t < T_STEPS; ++t) {
    float FB = 0.f;
#pragma unroll
    for (int j = 0; j < NA; ++j) FB = fmaf(Bsl[hb + j], commL[j], FB);
    float Q = 0.f, S = 0.f;
    for (int i = 0; i < NA; ++i, ++s) {
      int sn = s + 1; if (sn > STEPS_PER_RUN - 1) sn = STEPS_PER_RUN - 1;
      const float* xn = xbase + (size_t)sn * XS;
      xsl[h] = xa;
      if (h < XS - 64) xsl[64 + h] = xb;
      __syncthreads();
      float xa_n = xn[h];
      float xb_n = (h < XS - 64) ? xn[64 + h] : 0.f;
      float a0 = b1h, a1 = 0.f, a2 = 0.f;
#pragma unroll 4
      for (int k = 0; k < 31; ++k) {
        a0 = fmaf(xsl[3 * k],     w1xs[(3 * k) * HID + h],     a0);
        a1 = fmaf(xsl[3 * k + 1], w1xs[(3 * k + 1) * HID + h], a1);
        a2 = fmaf(xsl[3 * k + 2], w1xs[(3 * k + 2) * HID + h], a2);
      }
      float old_i = commL[i];
      S = fmaf(Bsl[hb + i], old_i, S);
      float h1 = fast_tanh(((a0 + a1) + a2) + FB + Q - S);
      h1s[h] = h1;
      __syncthreads();
      float c0 = b2h, c1 = 0.f, c2 = 0.f, c3 = 0.f;
      const float4* hv4 = (const float4*)h1s;
#pragma unroll
      for (int k4 = 0; k4 < 16; ++k4) {
        float4 hv = hv4[k4];
        c0 = fmaf(w2r[4 * k4 + 0], hv.x, c0);
        c1 = fmaf(w2r[4 * k4 + 1], hv.y, c1);
        c2 = fmaf(w2r[4 * k4 + 2], hv.z, c2);
        c3 = fmaf(w2r[4 * k4 + 3], hv.w, c3);
      }
      float h2 = fast_tanh((c0 + c1) + (c2 + c3));
      float o0 = wave64_sum_bcast(w30h * h2) + b30;
      float o1 = wave64_sum_bcast(w31h * h2) + b31;
      float c_new = wave64_sum_bcast(w32h * h2) + b32;
      if (h == 0) *(float2*)(outp + (size_t)s * 2) = make_float2(o0, o1);
      Q = fmaf(Asl[hb + i], c_new, Q);
      if (h == i) commL[h] = c_new;
      __syncthreads();
      xa = xa_n; xb = xb_n;
    }
  }
}

extern "C" void kernel_launch(void* const* d_in, const int* in_sizes, int n_in,
                              void* d_out, int out_size, void* d_ws, size_t ws_size,
                              hipStream_t stream) {
  const float* runs = (const float*)d_in[0];
  const float* comm_init = (const float*)d_in[1];
  const float* w1 = (const float*)d_in[2];
  const float* b1 = (const float*)d_in[3];
  const float* w2 = (const float*)d_in[4];
  const float* b2 = (const float*)d_in[5];
  const float* w3 = (const float*)d_in[6];
  const float* b3 = (const float*)d_in[7];
  float* out = (float*)d_out;

  if (ws_size >= WS_NEEDED) {
    float* w1T = (float*)d_ws;
    float* pre1 = (float*)((char*)d_ws + PRE1_OFF);
    hipLaunchKernelGGL(transpose_w1, dim3((XS * HID + 255) / 256), dim3(256), 0, stream,
                       w1, w1T);
    hipLaunchKernelGGL(pre1_kernel, dim3(RTI_TOT / 4), dim3(256), 0, stream,
                       runs, w1T, b1, pre1);
    hipLaunchKernelGGL(seq_kernel, dim3(R_RUNS), dim3(64), 0, stream,
                       w1, w2, b2, w3, b3, comm_init, pre1, out);
  } else {
    hipLaunchKernelGGL(seq_fused, dim3(R_RUNS), dim3(64), 0, stream,
                       runs, comm_init, w1, b1, w2, b2, w3, b3, out);
  }
}

// Round 6
// 6018.611 us; speedup vs baseline: 1.5597x; 1.2211x over previous
//
#include <hip/hip_runtime.h>

// ---------------------------------------------------------------------------
// ComNet: R=16 runs x T=512 steps x 32 agents, sequential agent scan.
//   k0: transpose W1[:, :93] -> w1T
//   k1: pre1[rti][h] = b1[h] + xs(93) . W1xs  (parallel, bulk of FLOPs)
//   k2: wave-synchronous sequential kernel, 16 blocks x 1 wave.
// Round-1: __syncthreads forces vmcnt(0) drains -> removed.
// Round-2: per-step global store / on-chain readlane -> LDS ring + snapshot.
// Round-4: ballast: clock/DPM hypothesis dead.
// Round-5: W2 row as 16 named float4 -> VGPR 76->96, 8631->6827us. Scratch
//   reload theory confirmed. Remaining ~1000 cyc/step: h1 LDS round trip
//   (16 b128 @ ~12cyc pipe + ~120 latency), DPP reduce, 2 tanh.
// Round-6: (a) h1 via LDS in FP16 -> 8 b128 reads + v_dot2_f32_f16;
//   (b) clampless tanh 1-2/(e^2x+1); (c) only c_new reduce on-chain,
//   o0/o1 12-DPP reduce sunk after the Q update (fills next LDS turnaround).
// ---------------------------------------------------------------------------

#define R_RUNS 16
#define T_STEPS 512
#define NA 32
#define HID 64
#define XS 93                       // (NA-1)*3
#define DIN 124
#define STEPS_PER_RUN (T_STEPS * NA)        // 16384
#define RTI_TOT (R_RUNS * STEPS_PER_RUN)    // 262144

#define PRE1_OFF 65536
#define WS_NEEDED ((size_t)PRE1_OFF + (size_t)RTI_TOT * HID * 4 + 4096)

typedef _Float16 half2_t __attribute__((ext_vector_type(2)));

__device__ __forceinline__ float fast_tanh(float x) {
  // tanh(x) = 1 - 2/(e^{2x}+1); exp overflow -> rcp(inf)=0 -> 1, exp(-inf)=0
  // -> -1: no clamp needed.
  float e = __expf(2.f * x);
  return fmaf(-2.f, __builtin_amdgcn_rcpf(e + 1.f), 1.f);
}

__device__ __forceinline__ float dot2h(half2_t a, half2_t b, float c) {
#if __has_builtin(__builtin_amdgcn_fdot2)
  return __builtin_amdgcn_fdot2(a, b, c, false);
#else
  return fmaf((float)a.x, (float)b.x, fmaf((float)a.y, (float)b.y, c));
#endif
}

#define DPP_ADD(x, ctrl, rmask) \
  (x) += __int_as_float(__builtin_amdgcn_update_dpp(0, __float_as_int(x), (ctrl), (rmask), 0xf, true))

__device__ __forceinline__ float wave64_sum_bcast(float x) {
  DPP_ADD(x, 0x111, 0xf);
  DPP_ADD(x, 0x112, 0xf);
  DPP_ADD(x, 0x114, 0xf);
  DPP_ADD(x, 0x118, 0xf);
  DPP_ADD(x, 0x142, 0xa);
  DPP_ADD(x, 0x143, 0xc);
  return __int_as_float(__builtin_amdgcn_readlane(__float_as_int(x), 63));
}

// two interleaved sums, totals left in lane 63 (consumer is lane 63)
__device__ __forceinline__ void wave64_sum2_l63(float& x0, float& x1) {
#define ST2(ctrl, rmask) DPP_ADD(x0, ctrl, rmask); DPP_ADD(x1, ctrl, rmask)
  ST2(0x111, 0xf);
  ST2(0x112, 0xf);
  ST2(0x114, 0xf);
  ST2(0x118, 0xf);
  ST2(0x142, 0xa);
  ST2(0x143, 0xc);
#undef ST2
}

// ---------------- k0: transpose W1 xs-part ----------------
__global__ void transpose_w1(const float* __restrict__ w1, float* __restrict__ w1T) {
  int idx = blockIdx.x * blockDim.x + threadIdx.x;  // idx = k*64 + h
  if (idx < XS * HID) {
    int k = idx / HID, h = idx % HID;
    w1T[idx] = w1[h * DIN + k];
  }
}

// ---------------- k1: pre1 = b1 + xs @ W1xs^T ----------------
__global__ __launch_bounds__(256) void pre1_kernel(
    const float* __restrict__ runs, const float* __restrict__ w1T,
    const float* __restrict__ b1, float* __restrict__ pre1) {
  const int wid = (blockIdx.x * 256 + threadIdx.x) >> 6;  // rti, one wave each
  const int lane = threadIdx.x & 63;
  const float* xs = runs + (size_t)wid * XS;   // wave-uniform: broadcast loads
  float a0 = b1[lane], a1 = 0.f, a2 = 0.f;
#pragma unroll 4
  for (int k = 0; k < 31; ++k) {
    a0 = fmaf(xs[3 * k],     w1T[(3 * k) * HID + lane],     a0);
    a1 = fmaf(xs[3 * k + 1], w1T[(3 * k + 1) * HID + lane], a1);
    a2 = fmaf(xs[3 * k + 2], w1T[(3 * k + 2) * HID + lane], a2);
  }
  pre1[(size_t)wid * HID + lane] = (a0 + a1) + a2;
}

// ---------------- k2: sequential core (wave-synchronous) ----------------
// A[h][j] = w1[h][93+j] (j<=30, A[h][31]=0) : weight of comm[j] when j<i
// B[h][j] = w1[h][92+j] (j>=1,  B[h][0]=0)  : weight of comm[j] when j>i
// h1pre = pre1 + FB + Q - S; FB = sum_j B*comm_t0[j] (refresh each t),
// S += B[h][i]*old_i (old_i from t-start snapshot), Q += A[h][i]*c_new.
__global__ __launch_bounds__(64, 1) void seq_kernel(
    const float* __restrict__ w1, const float* __restrict__ w2,
    const float* __restrict__ b2, const float* __restrict__ w3,
    const float* __restrict__ b3, const float* __restrict__ comm_init,
    const float* __restrict__ pre1, float* __restrict__ out) {
  const int h = threadIdx.x;
  const int r = blockIdx.x;
  const int hb = h * 33;              // stride 33: conflict-free

  __shared__ float Asl[HID * 33];
  __shared__ float Bsl[HID * 33];
  __shared__ __align__(16) float commL[NA];
  __shared__ __align__(16) _Float16 h1s16[HID];   // h1 in fp16: 128B, 8 b128 reads
  __shared__ __align__(16) float2 oL[NA];   // per-t (o0,o1) ring, flushed per t

  for (int j = 0; j < 31; ++j) Asl[hb + j] = w1[h * DIN + 93 + j];
  Asl[hb + 31] = 0.f;
  Bsl[hb] = 0.f;
  for (int j = 1; j < 32; ++j) Bsl[hb + j] = w1[h * DIN + 92 + j];

  // W2 row h -> 32 NAMED half2 (no array -> no SROA demotion; 32 VGPRs).
  const float4* w2v = (const float4*)(w2 + h * HID);
  const float4 r0 = w2v[0],  r1 = w2v[1],  r2 = w2v[2],  r3 = w2v[3];
  const float4 r4 = w2v[4],  r5 = w2v[5],  r6 = w2v[6],  r7 = w2v[7];
  const float4 r8 = w2v[8],  r9 = w2v[9],  r10 = w2v[10], r11 = w2v[11];
  const float4 r12 = w2v[12], r13 = w2v[13], r14 = w2v[14], r15 = w2v[15];
#define PK2(n, f4) \
  const half2_t n##a = {(_Float16)(f4).x, (_Float16)(f4).y}; \
  const half2_t n##b = {(_Float16)(f4).z, (_Float16)(f4).w}
  PK2(q0, r0);  PK2(q1, r1);  PK2(q2, r2);  PK2(q3, r3);
  PK2(q4, r4);  PK2(q5, r5);  PK2(q6, r6);  PK2(q7, r7);
  PK2(q8, r8);  PK2(q9, r9);  PK2(q10, r10); PK2(q11, r11);
  PK2(q12, r12); PK2(q13, r13); PK2(q14, r14); PK2(q15, r15);
#undef PK2

  const float b2h = b2[h];
  const float w30h = w3[h], w31h = w3[HID + h], w32h = w3[2 * HID + h];
  const float b30 = b3[0], b31 = b3[1], b32 = b3[2];

  float commR = (h < NA) ? comm_init[r * NA + h] : 0.f;  // lane j holds comm[j]
  if (h < NA) commL[h] = commR;                          // mirror for FB refresh

  const float* p = pre1 + (size_t)r * STEPS_PER_RUN * HID + h;
  float pf[4];                         // prefetch ring, depth 4 (const-indexed)
  pf[0] = p[0]; pf[1] = p[HID]; pf[2] = p[2 * HID]; pf[3] = p[3 * HID];
  float* outw = out + (size_t)r * STEPS_PER_RUN * 2;

  for (int t = 0; t < T_STEPS; ++t) {
    // FB refresh (amortized over 32 steps)
    const float4* cv4 = (const float4*)commL;
    float f0 = 0.f, f1 = 0.f, f2 = 0.f, f3 = 0.f;
#pragma unroll
    for (int q = 0; q < 8; ++q) {
      float4 c = cv4[q];
      f0 = fmaf(Bsl[hb + 4 * q + 0], c.x, f0);
      f1 = fmaf(Bsl[hb + 4 * q + 1], c.y, f1);
      f2 = fmaf(Bsl[hb + 4 * q + 2], c.z, f2);
      f3 = fmaf(Bsl[hb + 4 * q + 3], c.w, f3);
    }
    const float FB = (f0 + f1) + (f2 + f3);
    const float c0s = commR;           // t-start snapshot: old_i source, off-chain
    float Q = 0.f, S = 0.f;

#pragma unroll 4
    for (int i = 0; i < NA; ++i) {
      float pin = p[(i + 4) * HID];    // fire-and-forget prefetch, depth 4
      float A_i = Asl[hb + i];         // off-chain LDS loads
      float B_i = Bsl[hb + i];
      float old_i = __int_as_float(__builtin_amdgcn_readlane(__float_as_int(c0s), i));
      S = fmaf(B_i, old_i, S);         // off the c_new chain (snapshot-based)
      float h1 = fast_tanh(pf[i & 3] + (FB - S) + Q);   // chain: Q enters here
      pf[i & 3] = pin;
      h1s16[h] = (_Float16)h1;         // fp16 store: 128B total
      // 64-term dot via 32 v_dot2_f32_f16, 4 accumulator chains
      const uint4* hv = (const uint4*)h1s16;   // broadcast reads, 8 b128
      uint4 X0 = hv[0], X1 = hv[1], X2 = hv[2], X3 = hv[3];
      uint4 X4 = hv[4], X5 = hv[5], X6 = hv[6], X7 = hv[7];
#define BC(u) __builtin_bit_cast(half2_t, (u))
      float a0 = b2h, a1 = 0.f, a2 = 0.f, a3 = 0.f;
#define DOTB(Xq, qe, qo) \
      a0 = dot2h(qe##a, BC(Xq.x), a0); a1 = dot2h(qe##b, BC(Xq.y), a1); \
      a2 = dot2h(qo##a, BC(Xq.z), a2); a3 = dot2h(qo##b, BC(Xq.w), a3)
      DOTB(X0, q0, q1);   DOTB(X1, q2, q3);
      DOTB(X2, q4, q5);   DOTB(X3, q6, q7);
      DOTB(X4, q8, q9);   DOTB(X5, q10, q11);
      DOTB(X6, q12, q13); DOTB(X7, q14, q15);
#undef DOTB
#undef BC
      float h2 = fast_tanh((a0 + a1) + (a2 + a3));
      // --- on-chain: c_new reduce only (6 dependent DPP + readlane) ---
      float c_new = wave64_sum_bcast(w32h * h2) + b32;
      Q = fmaf(A_i, c_new, Q);
      commR = (h == i) ? c_new : commR;
      if (h == i) commL[h] = c_new;    // mirror for next t's FB, off-chain
      // --- off-chain: o0/o1 reduce, sinks into next step's LDS turnaround ---
      float s0 = w30h * h2, s1 = w31h * h2;
      wave64_sum2_l63(s0, s1);         // totals in lane 63
      if (h == 63) oL[i] = make_float2(s0 + b30, s1 + b31);
    }
    p += NA * HID;
    // flush this t's 32 x (o0,o1) = 64 floats, one coalesced 256B store.
    outw[h] = ((const float*)oL)[h];
    outw += 2 * NA;
  }
}

// ---------------- fallback: fully fused, zero workspace (unused when ws ok) --
__global__ __launch_bounds__(64, 1) void seq_fused(
    const float* __restrict__ runs, const float* __restrict__ comm_init,
    const float* __restrict__ w1, const float* __restrict__ b1,
    const float* __restrict__ w2, const float* __restrict__ b2,
    const float* __restrict__ w3, const float* __restrict__ b3,
    float* __restrict__ out) {
  const int r = blockIdx.x;
  const int h = threadIdx.x;
  const int hb = h * 33;

  __shared__ float Asl[HID * 33];
  __shared__ float Bsl[HID * 33];
  __shared__ float commL[NA];
  __shared__ __align__(16) float h1s[HID];
  __shared__ float w1xs[XS * HID];
  __shared__ __align__(16) float xsl[96];

  for (int j = 0; j < 31; ++j) Asl[hb + j] = w1[h * DIN + 93 + j];
  Asl[hb + 31] = 0.f;
  Bsl[hb] = 0.f;
  for (int j = 1; j < 32; ++j) Bsl[hb + j] = w1[h * DIN + 92 + j];
  for (int k = 0; k < XS; ++k) w1xs[k * HID + h] = w1[h * DIN + k];

  float w2r[HID];
#pragma unroll
  for (int k = 0; k < HID; ++k) w2r[k] = w2[h * HID + k];
  const float b1h = b1[h];
  const float b2h = b2[h];
  const float w30h = w3[h], w31h = w3[HID + h], w32h = w3[2 * HID + h];
  const float b30 = b3[0], b31 = b3[1], b32 = b3[2];
  if (h < NA) commL[h] = comm_init[r * NA + h];

  const float* xbase = runs + (size_t)r * STEPS_PER_RUN * XS;
  float xa = xbase[h];
  float xb = (h < XS - 64) ? xbase[64 + h] : 0.f;
  float* outp = out + (size_t)r * STEPS_PER_RUN * 2;
  __syncthreads();

  int s = 0;
  for (int t = 0; t < T_STEPS; ++t) {
    float FB = 0.f;
#pragma unroll
    for (int j = 0; j < NA; ++j) FB = fmaf(Bsl[hb + j], commL[j], FB);
    float Q = 0.f, S = 0.f;
    for (int i = 0; i < NA; ++i, ++s) {
      int sn = s + 1; if (sn > STEPS_PER_RUN - 1) sn = STEPS_PER_RUN - 1;
      const float* xn = xbase + (size_t)sn * XS;
      xsl[h] = xa;
      if (h < XS - 64) xsl[64 + h] = xb;
      __syncthreads();
      float xa_n = xn[h];
      float xb_n = (h < XS - 64) ? xn[64 + h] : 0.f;
      float a0 = b1h, a1 = 0.f, a2 = 0.f;
#pragma unroll 4
      for (int k = 0; k < 31; ++k) {
        a0 = fmaf(xsl[3 * k],     w1xs[(3 * k) * HID + h],     a0);
        a1 = fmaf(xsl[3 * k + 1], w1xs[(3 * k + 1) * HID + h], a1);
        a2 = fmaf(xsl[3 * k + 2], w1xs[(3 * k + 2) * HID + h], a2);
      }
      float old_i = commL[i];
      S = fmaf(Bsl[hb + i], old_i, S);
      float h1 = fast_tanh(((a0 + a1) + a2) + FB + Q - S);
      h1s[h] = h1;
      __syncthreads();
      float c0 = b2h, c1 = 0.f, c2 = 0.f, c3 = 0.f;
      const float4* hv4 = (const float4*)h1s;
#pragma unroll
      for (int k4 = 0; k4 < 16; ++k4) {
        float4 hv = hv4[k4];
        c0 = fmaf(w2r[4 * k4 + 0], hv.x, c0);
        c1 = fmaf(w2r[4 * k4 + 1], hv.y, c1);
        c2 = fmaf(w2r[4 * k4 + 2], hv.z, c2);
        c3 = fmaf(w2r[4 * k4 + 3], hv.w, c3);
      }
      float h2 = fast_tanh((c0 + c1) + (c2 + c3));
      float o0 = wave64_sum_bcast(w30h * h2) + b30;
      float o1 = wave64_sum_bcast(w31h * h2) + b31;
      float c_new = wave64_sum_bcast(w32h * h2) + b32;
      if (h == 0) *(float2*)(outp + (size_t)s * 2) = make_float2(o0, o1);
      Q = fmaf(Asl[hb + i], c_new, Q);
      if (h == i) commL[h] = c_new;
      __syncthreads();
      xa = xa_n; xb = xb_n;
    }
  }
}

extern "C" void kernel_launch(void* const* d_in, const int* in_sizes, int n_in,
                              void* d_out, int out_size, void* d_ws, size_t ws_size,
                              hipStream_t stream) {
  const float* runs = (const float*)d_in[0];
  const float* comm_init = (const float*)d_in[1];
  const float* w1 = (const float*)d_in[2];
  const float* b1 = (const float*)d_in[3];
  const float* w2 = (const float*)d_in[4];
  const float* b2 = (const float*)d_in[5];
  const float* w3 = (const float*)d_in[6];
  const float* b3 = (const float*)d_in[7];
  float* out = (float*)d_out;

  if (ws_size >= WS_NEEDED) {
    float* w1T = (float*)d_ws;
    float* pre1 = (float*)((char*)d_ws + PRE1_OFF);
    hipLaunchKernelGGL(transpose_w1, dim3((XS * HID + 255) / 256), dim3(256), 0, stream,
                       w1, w1T);
    hipLaunchKernelGGL(pre1_kernel, dim3(RTI_TOT / 4), dim3(256), 0, stream,
                       runs, w1T, b1, pre1);
    hipLaunchKernelGGL(seq_kernel, dim3(R_RUNS), dim3(64), 0, stream,
                       w1, w2, b2, w3, b3, comm_init, pre1, out);
  } else {
    hipLaunchKernelGGL(seq_fused, dim3(R_RUNS), dim3(64), 0, stream,
                       runs, comm_init, w1, b1, w2, b2, w3, b3, out);
  }
}

// Round 7
// 5568.895 us; speedup vs baseline: 1.6857x; 1.0808x over previous
//
#include <hip/hip_runtime.h>

// ---------------------------------------------------------------------------
// ComNet: R=16 runs x T=512 steps x 32 agents, sequential agent scan.
//   k0: transpose W1[:, :93] -> w1T
//   k1: pre1[rti][h] = b1[h] + xs(93) . W1xs  (parallel, bulk of FLOPs)
//   k2: wave-synchronous sequential kernel, 16 blocks x 1 wave.
// R1: __syncthreads forces vmcnt(0) drains -> removed.
// R2: per-step global store / on-chain readlane -> LDS ring + snapshot.
// R4: ballast: clock/DPM hypothesis dead.
// R5: W2 row as named float4 -> VGPR 76->96, scratch-reload theory confirmed.
// R6: fp16 h1 LDS + v_dot2 + clampless tanh + off-chain o0/o1: 6827->5520us.
// R7: prove the pf path off-chain. pre1 t-rows staged through a double-
//   buffered LDS ring (regs loaded at top of t, ds_written at end of t);
//   per-step pf is a 1-ahead ds_read of t-old data. A/B pipelined 1 ahead.
//   commL mirror written once per t. No global access near the chain.
// ---------------------------------------------------------------------------

#define R_RUNS 16
#define T_STEPS 512
#define NA 32
#define HID 64
#define XS 93                       // (NA-1)*3
#define DIN 124
#define STEPS_PER_RUN (T_STEPS * NA)        // 16384
#define RTI_TOT (R_RUNS * STEPS_PER_RUN)    // 262144

#define PRE1_OFF 65536
#define WS_NEEDED ((size_t)PRE1_OFF + (size_t)RTI_TOT * HID * 4 + 4096)

typedef _Float16 half2_t __attribute__((ext_vector_type(2)));

__device__ __forceinline__ float fast_tanh(float x) {
  // tanh(x) = 1 - 2/(e^{2x}+1); exp(+inf)->rcp(inf)=0 -> 1; exp(-inf)=0 -> -1.
  float e = __expf(2.f * x);
  return fmaf(-2.f, __builtin_amdgcn_rcpf(e + 1.f), 1.f);
}

__device__ __forceinline__ float dot2h(half2_t a, half2_t b, float c) {
#if __has_builtin(__builtin_amdgcn_fdot2)
  return __builtin_amdgcn_fdot2(a, b, c, false);
#else
  return fmaf((float)a.x, (float)b.x, fmaf((float)a.y, (float)b.y, c));
#endif
}

#define DPP_ADD(x, ctrl, rmask) \
  (x) += __int_as_float(__builtin_amdgcn_update_dpp(0, __float_as_int(x), (ctrl), (rmask), 0xf, true))

__device__ __forceinline__ float wave64_sum_bcast(float x) {
  DPP_ADD(x, 0x111, 0xf);
  DPP_ADD(x, 0x112, 0xf);
  DPP_ADD(x, 0x114, 0xf);
  DPP_ADD(x, 0x118, 0xf);
  DPP_ADD(x, 0x142, 0xa);
  DPP_ADD(x, 0x143, 0xc);
  return __int_as_float(__builtin_amdgcn_readlane(__float_as_int(x), 63));
}

// two interleaved sums, totals left in lane 63 (consumer is lane 63)
__device__ __forceinline__ void wave64_sum2_l63(float& x0, float& x1) {
#define ST2(ctrl, rmask) DPP_ADD(x0, ctrl, rmask); DPP_ADD(x1, ctrl, rmask)
  ST2(0x111, 0xf);
  ST2(0x112, 0xf);
  ST2(0x114, 0xf);
  ST2(0x118, 0xf);
  ST2(0x142, 0xa);
  ST2(0x143, 0xc);
#undef ST2
}

// ---------------- k0: transpose W1 xs-part ----------------
__global__ void transpose_w1(const float* __restrict__ w1, float* __restrict__ w1T) {
  int idx = blockIdx.x * blockDim.x + threadIdx.x;  // idx = k*64 + h
  if (idx < XS * HID) {
    int k = idx / HID, h = idx % HID;
    w1T[idx] = w1[h * DIN + k];
  }
}

// ---------------- k1: pre1 = b1 + xs @ W1xs^T ----------------
__global__ __launch_bounds__(256) void pre1_kernel(
    const float* __restrict__ runs, const float* __restrict__ w1T,
    const float* __restrict__ b1, float* __restrict__ pre1) {
  const int wid = (blockIdx.x * 256 + threadIdx.x) >> 6;  // rti, one wave each
  const int lane = threadIdx.x & 63;
  const float* xs = runs + (size_t)wid * XS;   // wave-uniform: broadcast loads
  float a0 = b1[lane], a1 = 0.f, a2 = 0.f;
#pragma unroll 4
  for (int k = 0; k < 31; ++k) {
    a0 = fmaf(xs[3 * k],     w1T[(3 * k) * HID + lane],     a0);
    a1 = fmaf(xs[3 * k + 1], w1T[(3 * k + 1) * HID + lane], a1);
    a2 = fmaf(xs[3 * k + 2], w1T[(3 * k + 2) * HID + lane], a2);
  }
  pre1[(size_t)wid * HID + lane] = (a0 + a1) + a2;
}

// ---------------- k2: sequential core (wave-synchronous) ----------------
// A[h][j] = w1[h][93+j] (j<=30, pad 0) : weight of comm[j] when j<i
// B[h][j] = w1[h][92+j] (j>=1,  pad 0) : weight of comm[j] when j>i
// h1pre = pre1 + FB + Q - S; FB = sum_j B*comm_t0[j] (refresh each t),
// S += B[h][i]*old_i (old_i from t-start snapshot), Q += A[h][i]*c_new.
__global__ __launch_bounds__(64, 1) void seq_kernel(
    const float* __restrict__ w1, const float* __restrict__ w2,
    const float* __restrict__ b2, const float* __restrict__ w3,
    const float* __restrict__ b3, const float* __restrict__ comm_init,
    const float* __restrict__ pre1, float* __restrict__ out) {
  const int h = threadIdx.x;
  const int r = blockIdx.x;
  const int hb = h * 33;              // stride 33: conflict-free, +pad entry 32

  __shared__ float Asl[HID * 33];
  __shared__ float Bsl[HID * 33];
  __shared__ __align__(16) float commL[NA];
  __shared__ __align__(16) _Float16 h1s16[HID];   // h1 fp16: 128B, 8 b128 reads
  __shared__ __align__(16) float2 oL[NA];         // per-t (o0,o1), flushed per t
  __shared__ __align__(16) float pbuf[2][2048 + 64];  // t-row ring + pad read slot

  for (int j = 0; j < 31; ++j) Asl[hb + j] = w1[h * DIN + 93 + j];
  Asl[hb + 31] = 0.f;
  Asl[hb + 32] = 0.f;                 // pad: A_next read at i=31
  Bsl[hb] = 0.f;
  for (int j = 1; j < 32; ++j) Bsl[hb + j] = w1[h * DIN + 92 + j];
  Bsl[hb + 32] = 0.f;                 // pad: B_next read at i=31

  // W2 row h -> 32 NAMED half2 (no array -> no SROA demotion).
  const float4* w2v = (const float4*)(w2 + h * HID);
  const float4 r0 = w2v[0],  r1 = w2v[1],  r2 = w2v[2],  r3 = w2v[3];
  const float4 r4 = w2v[4],  r5 = w2v[5],  r6 = w2v[6],  r7 = w2v[7];
  const float4 r8 = w2v[8],  r9 = w2v[9],  r10 = w2v[10], r11 = w2v[11];
  const float4 r12 = w2v[12], r13 = w2v[13], r14 = w2v[14], r15 = w2v[15];
#define PK2(n, f4) \
  const half2_t n##a = {(_Float16)(f4).x, (_Float16)(f4).y}; \
  const half2_t n##b = {(_Float16)(f4).z, (_Float16)(f4).w}
  PK2(q0, r0);  PK2(q1, r1);  PK2(q2, r2);  PK2(q3, r3);
  PK2(q4, r4);  PK2(q5, r5);  PK2(q6, r6);  PK2(q7, r7);
  PK2(q8, r8);  PK2(q9, r9);  PK2(q10, r10); PK2(q11, r11);
  PK2(q12, r12); PK2(q13, r13); PK2(q14, r14); PK2(q15, r15);
#undef PK2

  const float b2h = b2[h];
  const float w30h = w3[h], w31h = w3[HID + h], w32h = w3[2 * HID + h];
  const float b30 = b3[0], b31 = b3[1], b32 = b3[2];

  float commR = (h < NA) ? comm_init[r * NA + h] : 0.f;  // lane j holds comm[j]
  if (h < NA) commL[h] = commR;                          // mirror for FB refresh

  const float* prow = pre1 + (size_t)r * STEPS_PER_RUN * HID;  // + t*2048 floats

  // prime rows 0 and 1 into the LDS ring (one-time)
  {
    const float4* s0 = (const float4*)prow;
    const float4* s1 = (const float4*)(prow + 2048);
    float4* d0 = (float4*)&pbuf[0][0];
    float4* d1 = (float4*)&pbuf[1][0];
#pragma unroll
    for (int j = 0; j < 8; ++j) d0[j * 64 + h] = s0[j * 64 + h];
#pragma unroll
    for (int j = 0; j < 8; ++j) d1[j * 64 + h] = s1[j * 64 + h];
  }

  float* outw = out + (size_t)r * STEPS_PER_RUN * 2;

  for (int t = 0; t < T_STEPS; ++t) {
    float* pb = pbuf[t & 1];
    // prefetch row t+2 into 8 named float4 regs; retires during the ~13k-cyc
    // body; consumed by the ds_writes at the end of this t. Fully off-chain.
    int tk = (t + 2 <= T_STEPS - 1) ? t + 2 : T_STEPS - 1;
    const float4* gsrc = (const float4*)(prow + (size_t)tk * 2048);
    float4 g0 = gsrc[0 * 64 + h], g1 = gsrc[1 * 64 + h];
    float4 g2 = gsrc[2 * 64 + h], g3 = gsrc[3 * 64 + h];
    float4 g4 = gsrc[4 * 64 + h], g5 = gsrc[5 * 64 + h];
    float4 g6 = gsrc[6 * 64 + h], g7 = gsrc[7 * 64 + h];

    // FB refresh (amortized over 32 steps); commL was finalized at end of t-1.
    const float4* cv4 = (const float4*)commL;
    float f0 = 0.f, f1 = 0.f, f2 = 0.f, f3 = 0.f;
#pragma unroll
    for (int q = 0; q < 8; ++q) {
      float4 c = cv4[q];
      f0 = fmaf(Bsl[hb + 4 * q + 0], c.x, f0);
      f1 = fmaf(Bsl[hb + 4 * q + 1], c.y, f1);
      f2 = fmaf(Bsl[hb + 4 * q + 2], c.z, f2);
      f3 = fmaf(Bsl[hb + 4 * q + 3], c.w, f3);
    }
    const float FB = (f0 + f1) + (f2 + f3);
    const float c0s = commR;           // t-start snapshot: old_i source, off-chain
    float Q = 0.f, S = 0.f;
    float pf_cur = pb[h];              // step-0 value (hidden under FB refresh)
    float A_cur = Asl[hb], B_cur = Bsl[hb];

#pragma unroll 4
    for (int i = 0; i < NA; ++i) {
      // 1-ahead pipelined LDS reads (i=31 hits the pad slot / entry 32 -> unused)
      float pf_n = pb[(i + 1) * 64 + h];
      float A_n = Asl[hb + i + 1];
      float B_n = Bsl[hb + i + 1];
      float old_i = __int_as_float(__builtin_amdgcn_readlane(__float_as_int(c0s), i));
      S = fmaf(B_cur, old_i, S);       // off the c_new chain (snapshot-based)
      float h1 = fast_tanh(pf_cur + (FB - S) + Q);   // chain: Q enters here
      h1s16[h] = (_Float16)h1;         // fp16 store: 128B total
      // 64-term dot via 32 v_dot2_f32_f16, 4 accumulator chains
      const uint4* hv = (const uint4*)h1s16;   // broadcast reads, 8 b128
      uint4 X0 = hv[0], X1 = hv[1], X2 = hv[2], X3 = hv[3];
      uint4 X4 = hv[4], X5 = hv[5], X6 = hv[6], X7 = hv[7];
#define BC(u) __builtin_bit_cast(half2_t, (u))
      float a0 = b2h, a1 = 0.f, a2 = 0.f, a3 = 0.f;
#define DOTB(Xq, qe, qo) \
      a0 = dot2h(qe##a, BC(Xq.x), a0); a1 = dot2h(qe##b, BC(Xq.y), a1); \
      a2 = dot2h(qo##a, BC(Xq.z), a2); a3 = dot2h(qo##b, BC(Xq.w), a3)
      DOTB(X0, q0, q1);   DOTB(X1, q2, q3);
      DOTB(X2, q4, q5);   DOTB(X3, q6, q7);
      DOTB(X4, q8, q9);   DOTB(X5, q10, q11);
      DOTB(X6, q12, q13); DOTB(X7, q14, q15);
#undef DOTB
#undef BC
      float h2 = fast_tanh((a0 + a1) + (a2 + a3));
      // --- on-chain: c_new reduce only (6 dependent DPP + readlane) ---
      float c_new = wave64_sum_bcast(w32h * h2) + b32;
      Q = fmaf(A_cur, c_new, Q);
      commR = (h == i) ? c_new : commR;
      // --- off-chain: o0/o1 reduce sinks into next step's LDS turnaround ---
      float s0v = w30h * h2, s1v = w31h * h2;
      wave64_sum2_l63(s0v, s1v);       // totals in lane 63
      if (h == 63) oL[i] = make_float2(s0v + b30, s1v + b31);
      pf_cur = pf_n; A_cur = A_n; B_cur = B_n;
    }
    if (h < NA) commL[h] = commR;      // mirror refresh, once per t
    // flush this t's 32 x (o0,o1) = 64 floats, one coalesced 256B store.
    outw[h] = ((const float*)oL)[h];
    outw += 2 * NA;
    // stage row t+2 into the buffer just freed (all reads of pb are done;
    // g-regs loaded a full body ago -> no vmcnt stall).
    float4* pd = (float4*)pb;
    pd[0 * 64 + h] = g0; pd[1 * 64 + h] = g1;
    pd[2 * 64 + h] = g2; pd[3 * 64 + h] = g3;
    pd[4 * 64 + h] = g4; pd[5 * 64 + h] = g5;
    pd[6 * 64 + h] = g6; pd[7 * 64 + h] = g7;
  }
}

// ---------------- fallback: fully fused, zero workspace (unused when ws ok) --
__global__ __launch_bounds__(64, 1) void seq_fused(
    const float* __restrict__ runs, const float* __restrict__ comm_init,
    const float* __restrict__ w1, const float* __restrict__ b1,
    const float* __restrict__ w2, const float* __restrict__ b2,
    const float* __restrict__ w3, const float* __restrict__ b3,
    float* __restrict__ out) {
  const int r = blockIdx.x;
  const int h = threadIdx.x;
  const int hb = h * 33;

  __shared__ float Asl[HID * 33];
  __shared__ float Bsl[HID * 33];
  __shared__ float commL[NA];
  __shared__ __align__(16) float h1s[HID];
  __shared__ float w1xs[XS * HID];
  __shared__ __align__(16) float xsl[96];

  for (int j = 0; j < 31; ++j) Asl[hb + j] = w1[h * DIN + 93 + j];
  Asl[hb + 31] = 0.f;
  Bsl[hb] = 0.f;
  for (int j = 1; j < 32; ++j) Bsl[hb + j] = w1[h * DIN + 92 + j];
  for (int k = 0; k < XS; ++k) w1xs[k * HID + h] = w1[h * DIN + k];

  float w2r[HID];
#pragma unroll
  for (int k = 0; k < HID; ++k) w2r[k] = w2[h * HID + k];
  const float b1h = b1[h];
  const float b2h = b2[h];
  const float w30h = w3[h], w31h = w3[HID + h], w32h = w3[2 * HID + h];
  const float b30 = b3[0], b31 = b3[1], b32 = b3[2];
  if (h < NA) commL[h] = comm_init[r * NA + h];

  const float* xbase = runs + (size_t)r * STEPS_PER_RUN * XS;
  float xa = xbase[h];
  float xb = (h < XS - 64) ? xbase[64 + h] : 0.f;
  float* outp = out + (size_t)r * STEPS_PER_RUN * 2;
  __syncthreads();

  int s = 0;
  for (int t = 0; t < T_STEPS; ++t) {
    float FB = 0.f;
#pragma unroll
    for (int j = 0; j < NA; ++j) FB = fmaf(Bsl[hb + j], commL[j], FB);
    float Q = 0.f, S = 0.f;
    for (int i = 0; i < NA; ++i, ++s) {
      int sn = s + 1; if (sn > STEPS_PER_RUN - 1) sn = STEPS_PER_RUN - 1;
      const float* xn = xbase + (size_t)sn * XS;
      xsl[h] = xa;
      if (h < XS - 64) xsl[64 + h] = xb;
      __syncthreads();
      float xa_n = xn[h];
      float xb_n = (h < XS - 64) ? xn[64 + h] : 0.f;
      float a0 = b1h, a1 = 0.f, a2 = 0.f;
#pragma unroll 4
      for (int k = 0; k < 31; ++k) {
        a0 = fmaf(xsl[3 * k],     w1xs[(3 * k) * HID + h],     a0);
        a1 = fmaf(xsl[3 * k + 1], w1xs[(3 * k + 1) * HID + h], a1);
        a2 = fmaf(xsl[3 * k + 2], w1xs[(3 * k + 2) * HID + h], a2);
      }
      float old_i = commL[i];
      S = fmaf(Bsl[hb + i], old_i, S);
      float h1 = fast_tanh(((a0 + a1) + a2) + FB + Q - S);
      h1s[h] = h1;
      __syncthreads();
      float c0 = b2h, c1 = 0.f, c2 = 0.f, c3 = 0.f;
      const float4* hv4 = (const float4*)h1s;
#pragma unroll
      for (int k4 = 0; k4 < 16; ++k4) {
        float4 hv = hv4[k4];
        c0 = fmaf(w2r[4 * k4 + 0], hv.x, c0);
        c1 = fmaf(w2r[4 * k4 + 1], hv.y, c1);
        c2 = fmaf(w2r[4 * k4 + 2], hv.z, c2);
        c3 = fmaf(w2r[4 * k4 + 3], hv.w, c3);
      }
      float h2 = fast_tanh((c0 + c1) + (c2 + c3));
      float o0 = wave64_sum_bcast(w30h * h2) + b30;
      float o1 = wave64_sum_bcast(w31h * h2) + b31;
      float c_new = wave64_sum_bcast(w32h * h2) + b32;
      if (h == 0) *(float2*)(outp + (size_t)s * 2) = make_float2(o0, o1);
      Q = fmaf(Asl[hb + i], c_new, Q);
      if (h == i) commL[h] = c_new;
      __syncthreads();
      xa = xa_n; xb = xb_n;
    }
  }
}

extern "C" void kernel_launch(void* const* d_in, const int* in_sizes, int n_in,
                              void* d_out, int out_size, void* d_ws, size_t ws_size,
                              hipStream_t stream) {
  const float* runs = (const float*)d_in[0];
  const float* comm_init = (const float*)d_in[1];
  const float* w1 = (const float*)d_in[2];
  const float* b1 = (const float*)d_in[3];
  const float* w2 = (const float*)d_in[4];
  const float* b2 = (const float*)d_in[5];
  const float* w3 = (const float*)d_in[6];
  const float* b3 = (const float*)d_in[7];
  float* out = (float*)d_out;

  if (ws_size >= WS_NEEDED) {
    float* w1T = (float*)d_ws;
    float* pre1 = (float*)((char*)d_ws + PRE1_OFF);
    hipLaunchKernelGGL(transpose_w1, dim3((XS * HID + 255) / 256), dim3(256), 0, stream,
                       w1, w1T);
    hipLaunchKernelGGL(pre1_kernel, dim3(RTI_TOT / 4), dim3(256), 0, stream,
                       runs, w1T, b1, pre1);
    hipLaunchKernelGGL(seq_kernel, dim3(R_RUNS), dim3(64), 0, stream,
                       w1, w2, b2, w3, b3, comm_init, pre1, out);
  } else {
    hipLaunchKernelGGL(seq_fused, dim3(R_RUNS), dim3(64), 0, stream,
                       runs, comm_init, w1, b1, w2, b2, w3, b3, out);
  }
}